// Round 7
// baseline (1089.072 us; speedup 1.0000x reference)
//
#include <hip/hip_runtime.h>

typedef float f32x4 __attribute__((ext_vector_type(4)));
typedef short bf16x8 __attribute__((ext_vector_type(8)));
typedef short bf16x4 __attribute__((ext_vector_type(4)));
typedef unsigned short u16;
typedef unsigned int u32;

#define SCALE 0.0625f
#define MFMA32(a, b, c) __builtin_amdgcn_mfma_f32_16x16x32_bf16((a), (b), (c), 0, 0, 0)

#if __has_builtin(__builtin_amdgcn_mfma_f32_16x16x16_bf16)
#define MFMA16(a, b, c) __builtin_amdgcn_mfma_f32_16x16x16_bf16((a), (b), (c), 0, 0, 0)
#else
static __device__ __forceinline__ f32x4 MFMA16(bf16x4 a, bf16x4 b, f32x4 c) {
  asm("v_mfma_f32_16x16x16_bf16 %0, %1, %2, %0" : "+v"(c) : "v"(a), "v"(b));
  return c;
}
#endif

__device__ inline u16 f2bf(float x) {
  u32 u = __float_as_uint(x);
  u32 r = u + 0x7FFFu + ((u >> 16) & 1u);
  return (u16)(r >> 16);
}
__device__ inline float bf2f(u16 h) { return __uint_as_float(((u32)h) << 16); }

// async global->LDS, 16B per lane; LDS dest is wave-uniform base + lane*16
__device__ __forceinline__ void gld16(const void* g, void* l) {
  __builtin_amdgcn_global_load_lds(
      (const __attribute__((address_space(1))) unsigned int*)(uintptr_t)g,
      (__attribute__((address_space(3))) unsigned int*)(uintptr_t)l, 16, 0, 0);
}

// ---------------------------------------------------------------------------
// Transpose+split W matrices: W[k][n] fp32 -> Wt_hi/lo[n][k] bf16.
// ---------------------------------------------------------------------------
__global__ __launch_bounds__(256) void convert_w(
    const float* __restrict__ Wq, const float* __restrict__ Wk, const float* __restrict__ Wv,
    u16* __restrict__ qh, u16* __restrict__ qlo2, u16* __restrict__ kh, u16* __restrict__ klo2,
    u16* __restrict__ vh, u16* __restrict__ vlo2) {
  int idx = blockIdx.x * 256 + threadIdx.x;
  const float* src;
  u16 *dh, *dl;
  int KD;
  const int nq = 416 * 256;
  if (idx < nq) {
    src = Wq; dh = qh; dl = qlo2; KD = 416;
  } else if (idx < 2 * nq) {
    idx -= nq; src = Wk; dh = kh; dl = klo2; KD = 416;
  } else {
    idx -= 2 * nq;
    if (idx >= 384 * 256) return;
    src = Wv; dh = vh; dl = vlo2; KD = 384;
  }
  int k = idx >> 8, n = idx & 255;
  float x = src[idx];
  u16 h = f2bf(x);
  dh[n * KD + k] = h;
  dl[n * KD + k] = f2bf(x - bf2f(h));
}

// ---------------------------------------------------------------------------
// Projection GEMM, split-bf16 MFMA: C[m][256] = A[m][KD] @ W[KD][256].
// OUT=0: flat hi/lo [m][256] (Q).
// OUT=1: K into kvswz per-(km,kt16) 16384-u16 block:
//        Kh slot = row*256 + ((c ^ (row&7))<<3) + e   (row=j&15, c=d>>3, e=d&7)
//        Kl at +4096.
// OUT=2: V into same block: Vh slot = 8192 + (dt2*64 + (kk>>2)*16 + (d&15))*8
//        + (dt&1)*4 + (kk&3)   (dt=d>>4, dt2=d>>5, kk=j&15); Vl at +4096.
// ---------------------------------------------------------------------------
template <int KD, int OUT>
__global__ __launch_bounds__(256, 3) void proj_mfma(
    const float* __restrict__ A, const u16* __restrict__ wth, const u16* __restrict__ wtl,
    u16* __restrict__ oh, u16* __restrict__ ol) {
  __shared__ u16 Ah[64 * 32], Al[64 * 32];
  __shared__ u16 Wh[256 * 32], Wl[256 * 32];
  const int t = threadIdx.x;
  const int w = t >> 6, l = t & 63;
  const int lr = l & 15, lk = l >> 4;
  const int m0 = blockIdx.x * 64;
  f32x4 acc[16];
#pragma unroll
  for (int i = 0; i < 16; ++i) acc[i] = {};
  const int arow = t >> 2, ac = t & 3;
  const int acp = (ac + (arow >> 1)) & 3;
  for (int k0 = 0; k0 < KD; k0 += 32) {
    __syncthreads();
    {
      const float* s1 = A + (size_t)(m0 + arow) * KD + k0 + ac * 8;
      float4 f1 = *(const float4*)s1;
      float4 f2 = *(const float4*)(s1 + 4);
      float fs[8] = {f1.x, f1.y, f1.z, f1.w, f2.x, f2.y, f2.z, f2.w};
      bf16x8 hv, lv;
#pragma unroll
      for (int j = 0; j < 8; ++j) {
        u16 h = f2bf(fs[j]);
        hv[j] = (short)h;
        lv[j] = (short)f2bf(fs[j] - bf2f(h));
      }
      *(bf16x8*)(Ah + arow * 32 + acp * 8) = hv;
      *(bf16x8*)(Al + arow * 32 + acp * 8) = lv;
#pragma unroll
      for (int i = 0; i < 4; ++i) {
        int ch = t + i * 256;
        int n = ch >> 2, c = ch & 3;
        int cp = (c + (n >> 1)) & 3;
        *(bf16x8*)(Wh + n * 32 + cp * 8) = *(const bf16x8*)(wth + (size_t)n * KD + k0 + c * 8);
        *(bf16x8*)(Wl + n * 32 + cp * 8) = *(const bf16x8*)(wtl + (size_t)n * KD + k0 + c * 8);
      }
    }
    __syncthreads();
    const int row = w * 16 + lr;
    const int rcp = (lk + (row >> 1)) & 3;
    bf16x8 ah = *(const bf16x8*)(Ah + row * 32 + rcp * 8);
    bf16x8 al = *(const bf16x8*)(Al + row * 32 + rcp * 8);
#pragma unroll
    for (int fc = 0; fc < 16; ++fc) {
      int n = lr + 16 * fc;
      int cp = (lk + (n >> 1)) & 3;
      bf16x8 bh = *(const bf16x8*)(Wh + n * 32 + cp * 8);
      bf16x8 bl = *(const bf16x8*)(Wl + n * 32 + cp * 8);
      acc[fc] = MFMA32(ah, bh, acc[fc]);
      acc[fc] = MFMA32(ah, bl, acc[fc]);
      acc[fc] = MFMA32(al, bh, acc[fc]);
    }
  }
  if (OUT == 0) {
#pragma unroll
    for (int fc = 0; fc < 16; ++fc) {
      int n = lr + 16 * fc;
#pragma unroll
      for (int r = 0; r < 4; ++r) {
        int m = m0 + w * 16 + lk * 4 + r;
        float v = acc[fc][r];
        u16 h = f2bf(v);
        oh[(size_t)m * 256 + n] = h;
        ol[(size_t)m * 256 + n] = f2bf(v - bf2f(h));
      }
    }
  } else if (OUT == 1) {
#pragma unroll
    for (int r = 0; r < 4; ++r) {
      int m = m0 + w * 16 + lk * 4 + r;
      int km = m / 576;
      int j = m - km * 576;
      int kt = j >> 4, row = j & 15;
      size_t rowbase = ((size_t)(km * 36 + kt) << 14) + (row << 8);
      int rx = row & 7;
#pragma unroll
      for (int fc = 0; fc < 16; ++fc) {
        int c = (lr >> 3) + 2 * fc;
        size_t slot = rowbase + (size_t)(((c ^ rx) << 3) + (lr & 7));
        float v = acc[fc][r];
        u16 h = f2bf(v);
        oh[slot] = h;
        oh[slot + 4096] = f2bf(v - bf2f(h));
      }
    }
  } else {
    const int km = m0 / 576;
    const int j0 = (m0 % 576) + w * 16 + lk * 4;  // key row (r added below)
    const int kt = j0 >> 4;
    const size_t vbase = ((size_t)(km * 36 + kt) << 14) + 8192;
#pragma unroll
    for (int fc = 0; fc < 16; ++fc) {
      // d = lr + 16*fc: dt2 = fc>>1, half = fc&1, d&15 = lr; kk = lk*4 + r
      size_t slot = vbase + (size_t)((((fc >> 1) * 64 + lk * 16 + lr) << 3) + ((fc & 1) << 2));
      u16 hs[4], ls[4];
#pragma unroll
      for (int r = 0; r < 4; ++r) {
        float v = acc[fc][r];
        u16 h = f2bf(v);
        hs[r] = h;
        ls[r] = f2bf(v - bf2f(h));
      }
      *(ushort4*)(oh + slot) = make_ushort4(hs[0], hs[1], hs[2], hs[3]);
      *(ushort4*)(oh + slot + 4096) = make_ushort4(ls[0], ls[1], ls[2], ls[3]);
    }
  }
}

// ---------------------------------------------------------------------------
// Flash attention v2: 512 threads / 8 waves; block owns 128 q-rows of the
// flattened (b*576+n) = 2304 row space; each wave owns 16 distinct rows.
// kt = 16 keys; K/V hi+lo double-buffered (2 x 32 KB).  Swapped QK^T
// (S^T = mfma(K,Q), K=32) leaves each lane with 4 consecutive keys of one
// q-row == exactly the B-operand of mfma_16x16x16 -> PV is wave-local,
// P never touches LDS.  One barrier + one counted vmcnt per kt.
// m==0 softmax: P=exp(S*scale), stats per-lane, one shfl-reduce at end.
// R written normalized, layout [b,km][n][d] (coalesced f32x4 stores).
// ---------------------------------------------------------------------------
__global__ __launch_bounds__(512, 4) void attn_kernel(
    const u16* __restrict__ qhi, const u16* __restrict__ qlo,
    const u16* __restrict__ kvswz,
    float* __restrict__ rpartT, float* __restrict__ invl) {
  __shared__ u16 BUF[2][16384];  // per buf: [Kh 4096][Kl 4096][Vh 4096][Vl 4096]
  const int t = threadIdx.x;
  const int w = t >> 6, l = t & 63;
  const int lr = l & 15, lk = l >> 4;
  // XCD swizzle: 18 q-blocks of one km cluster on xcd = km%8
  const int L = blockIdx.x;
  const int xcd = L & 7, slot = L >> 3;
  const int km = xcd + 8 * (slot / 18);
  const int qb2 = slot % 18;
  const int myrow = qb2 * 128 + w * 16 + lr;  // lane's q-row (C col)
  const int b = myrow / 576, n = myrow - b * 576;

  // Q fragments (B-operand of swapped QK: col=q, k-chunk=lk*8 + s*32)
  bf16x8 qh[8], qlv[8];
  {
    const size_t qoff = (size_t)myrow * 256 + lk * 8;
#pragma unroll
    for (int s = 0; s < 8; ++s) {
      qh[s] = *(const bf16x8*)(qhi + qoff + s * 32);
      qlv[s] = *(const bf16x8*)(qlo + qoff + s * 32);
    }
  }

  f32x4 o[16];
#pragma unroll
  for (int i = 0; i < 16; ++i) o[i] = {};
  float m_part = -1e30f, l_part = 0.f;

  const char* kvb = (const char*)kvswz + (size_t)(km * 36) * 32768;

  auto STAGE = [&](int kt, u16* buf) {
    const char* src = kvb + (size_t)kt * 32768 + t * 16;
    char* dst = (char*)buf + t * 16;
#pragma unroll
    for (int rgn = 0; rgn < 4; ++rgn) gld16(src + rgn * 8192, dst + rgn * 8192);
  };

  // prologue: Q loads drained (clean vmcnt FIFO), then stage kt0, kt1.
  asm volatile("s_waitcnt vmcnt(0)" ::: "memory");
  __builtin_amdgcn_sched_barrier(0);
  STAGE(0, &BUF[0][0]);
  STAGE(1, &BUF[1][0]);
  asm volatile("s_waitcnt vmcnt(4)" ::: "memory");  // kt0 landed (kt1 in flight)
  __builtin_amdgcn_sched_barrier(0);
  __builtin_amdgcn_s_barrier();
  __builtin_amdgcn_sched_barrier(0);

  const int kx = lr & 7;

  auto STEP = [&](u16* buf, int kt) {
    // ---- QK^T (swapped): A = K-frag (16 keys), B = Q -> lane: q=l&15, keys lk*4+r
    f32x4 s0 = {};
    __builtin_amdgcn_s_setprio(1);
#pragma unroll
    for (int s = 0; s < 8; ++s) {
      const int c = ((s * 4 + lk) ^ kx) * 8;
      bf16x8 khf = *(const bf16x8*)(buf + lr * 256 + c);
      bf16x8 klf = *(const bf16x8*)(buf + 4096 + lr * 256 + c);
      s0 = MFMA32(khf, qh[s], s0);
      s0 = MFMA32(klf, qh[s], s0);
      s0 = MFMA32(khf, qlv[s], s0);
    }
    __builtin_amdgcn_s_setprio(0);

    // ---- P = exp(S*scale), in-register hi/lo bf16x4 (keys lk*4..+3)
    bf16x4 pa, pb;
#pragma unroll
    for (int r = 0; r < 4; ++r) {
      float a = s0[r] * SCALE;
      m_part = fmaxf(m_part, a);
      float e = __expf(a);
      l_part += e;
      u16 h = f2bf(e);
      pa[r] = (short)h;
      pb[r] = (short)f2bf(e - bf2f(h));
    }

    // ---- PV: wave-local, K=16 over its own 16 keys, all 256 d
    __builtin_amdgcn_s_setprio(1);
#pragma unroll
    for (int dt2 = 0; dt2 < 8; ++dt2) {
      bf16x8 vh8 = *(const bf16x8*)(buf + 8192 + (dt2 * 64 + l) * 8);
      bf16x8 vl8 = *(const bf16x8*)(buf + 12288 + (dt2 * 64 + l) * 8);
      bf16x4 vh0 = __builtin_shufflevector(vh8, vh8, 0, 1, 2, 3);
      bf16x4 vh1 = __builtin_shufflevector(vh8, vh8, 4, 5, 6, 7);
      bf16x4 vl0 = __builtin_shufflevector(vl8, vl8, 0, 1, 2, 3);
      bf16x4 vl1 = __builtin_shufflevector(vl8, vl8, 4, 5, 6, 7);
      o[dt2 * 2] = MFMA16(vh0, pa, o[dt2 * 2]);
      o[dt2 * 2] = MFMA16(vl0, pa, o[dt2 * 2]);
      o[dt2 * 2] = MFMA16(vh0, pb, o[dt2 * 2]);
      o[dt2 * 2 + 1] = MFMA16(vh1, pa, o[dt2 * 2 + 1]);
      o[dt2 * 2 + 1] = MFMA16(vl1, pa, o[dt2 * 2 + 1]);
      o[dt2 * 2 + 1] = MFMA16(vh1, pb, o[dt2 * 2 + 1]);
    }
    __builtin_amdgcn_s_setprio(0);

    // ---- single sync point: my LDS reads done, next buf landed, all waves ok
    asm volatile("s_waitcnt lgkmcnt(0)" ::: "memory");
    asm volatile("s_waitcnt vmcnt(0)" ::: "memory");
    __builtin_amdgcn_sched_barrier(0);
    __builtin_amdgcn_s_barrier();
    __builtin_amdgcn_sched_barrier(0);
    if (kt + 2 < 36) STAGE(kt + 2, buf);  // refill the buffer just consumed
    __builtin_amdgcn_sched_barrier(0);
  };

  for (int kt2 = 0; kt2 < 18; ++kt2) {
    STEP(&BUF[0][0], 2 * kt2);
    STEP(&BUF[1][0], 2 * kt2 + 1);
  }

  // ---- epilogue: per-lane stats reduce (combine 4 lk groups), all wave-local
  float lv = l_part, mv = m_part;
  lv += __shfl_xor(lv, 16, 64);
  mv = fmaxf(mv, __shfl_xor(mv, 16, 64));
  lv += __shfl_xor(lv, 32, 64);
  mv = fmaxf(mv, __shfl_xor(mv, 32, 64));
  float inv = 1.0f / lv;
  if (l < 16) invl[(size_t)(b * 80 + km) * 576 + n] = __expf(mv) * inv;

  float* dst = rpartT + ((size_t)(b * 80 + km) * 576 + n) * 256 + lk * 4;
#pragma unroll
  for (int dt = 0; dt < 16; ++dt) {
    f32x4 v = o[dt];
    v[0] *= inv; v[1] *= inv; v[2] *= inv; v[3] *= inv;
    *(f32x4*)(dst + dt * 16) = v;
  }
}

// ---------------------------------------------------------------------------
// Weights: s[b,k,m] = mean_n 1/l_ref ; w = gate(p) * s / (sum_m s + 1e-8)
// ---------------------------------------------------------------------------
__global__ __launch_bounds__(256) void weight_kernel(const float* __restrict__ invl,
                                                     const float* __restrict__ p,
                                                     float* __restrict__ wout) {
  const int k = blockIdx.x, b = blockIdx.y;
  __shared__ float sm[10];
  __shared__ float red[4];
  const int t = threadIdx.x;
  for (int m = 0; m < 10; ++m) {
    float part = 0.f;
    for (int n = t; n < 576; n += 256)
      part += invl[(size_t)((b * 8 + k) * 10 + m) * 576 + n];
#pragma unroll
    for (int off = 32; off; off >>= 1) part += __shfl_down(part, off, 64);
    if ((t & 63) == 0) red[t >> 6] = part;
    __syncthreads();
    if (t == 0) sm[m] = (red[0] + red[1] + red[2] + red[3]) * (1.0f / 576.0f);
    __syncthreads();
  }
  if (t == 0) {
    float tot = 0.f;
    for (int m = 0; m < 10; ++m) tot += sm[m];
    float pmax = fmaxf(fmaxf(p[0 * 8 + k], p[1 * 8 + k]), fmaxf(p[2 * 8 + k], p[3 * 8 + k]));
    float gate = (pmax >= 0.01f) ? p[b * 8 + k] : 0.0f;
    for (int m = 0; m < 10; ++m)
      wout[(b * 8 + k) * 10 + m] = gate * sm[m] / (tot + 1e-8f);
  }
}

// ---------------------------------------------------------------------------
// out[b][d][n] = sum_km w[b,km] * R[b,km][n][d]  (R is n-major now):
// coalesced reads along d, LDS-transposed coalesced writes along n.
// grid (576/32, 256/64, 4), 256 threads.
// ---------------------------------------------------------------------------
__global__ __launch_bounds__(256) void reduce_out_t(const float* __restrict__ R,
                                                    const float* __restrict__ wbuf,
                                                    float* __restrict__ out) {
  const int n0 = blockIdx.x * 32, d0 = blockIdx.y * 64, b = blockIdx.z;
  const int t = threadIdx.x;
  const int dn = t & 63, ng = t >> 6;
  float acc[8] = {};
  const float* wp = wbuf + b * 80;
  for (int g = 0; g < 80; ++g) {
    float wv = wp[g];
    const float* src = R + ((size_t)(b * 80 + g) * 576 + n0 + ng * 8) * 256 + d0 + dn;
#pragma unroll
    for (int i = 0; i < 8; ++i) acc[i] += wv * src[(size_t)i * 256];
  }
  __shared__ float tile[32][65];
#pragma unroll
  for (int i = 0; i < 8; ++i) tile[ng * 8 + i][dn] = acc[i];
  __syncthreads();
#pragma unroll
  for (int p = 0; p < 8; ++p) {
    int dd = p * 8 + (t >> 5);
    int nn = t & 31;
    out[((size_t)b * 256 + d0 + dd) * 576 + n0 + nn] = tile[nn][dd];
  }
}

// ---------------------------------------------------------------------------
extern "C" void kernel_launch(void* const* d_in, const int* in_sizes, int n_in,
                              void* d_out, int out_size, void* d_ws, size_t ws_size,
                              hipStream_t stream) {
  const float* Q = (const float*)d_in[0];
  const float* dbk = (const float*)d_in[1];
  const float* dbv = (const float*)d_in[2];
  const float* p = (const float*)d_in[3];
  const float* Wq = (const float*)d_in[4];
  const float* Wk = (const float*)d_in[5];
  const float* Wv = (const float*)d_in[6];
  float* out = (float*)d_out;
  char* ws = (char*)d_ws;

  u16* qhi = (u16*)(ws);                    // 1,179,648 B
  u16* qlo = (u16*)(ws + 1179648);          // 1,179,648 B
  u16* kvswz = (u16*)(ws + 2359296);        // 80*36*32768 = 94,371,840 B
  float* invl = (float*)(ws + 96731136);    // 737,280 B
  float* wbuf = (float*)(ws + 97468416);    // 1,280 B
  float* rpartT = (float*)(ws + 97469696);  // 188,743,680 B
  // W^T hi/lo temporaries aliased into rpartT region (consumed before attn writes)
  u16* wqh = (u16*)(ws + 97469696);
  u16* wql = wqh + 106496;
  u16* wkh = wql + 106496;
  u16* wkl = wkh + 106496;
  u16* wvh = wkl + 106496;
  u16* wvl = wvh + 98304;

  convert_w<<<1216, 256, 0, stream>>>(Wq, Wk, Wv, wqh, wql, wkh, wkl, wvh, wvl);
  proj_mfma<416, 0><<<36, 256, 0, stream>>>(Q, wqh, wql, qhi, qlo);
  proj_mfma<416, 1><<<720, 256, 0, stream>>>(dbk, wkh, wkl, kvswz, nullptr);
  proj_mfma<384, 2><<<720, 256, 0, stream>>>(dbv, wvh, wvl, kvswz, nullptr);
  attn_kernel<<<1440, 512, 0, stream>>>(qhi, qlo, kvswz, rpartT, invl);
  weight_kernel<<<dim3(8, 4), 256, 0, stream>>>(invl, p, wbuf);
  reduce_out_t<<<dim3(18, 4, 4), 256, 0, stream>>>(rpartT, wbuf, out);
}

// Round 8
// 751.254 us; speedup vs baseline: 1.4497x; 1.4497x over previous
//
#include <hip/hip_runtime.h>

typedef float f32x4 __attribute__((ext_vector_type(4)));
typedef short bf16x8 __attribute__((ext_vector_type(8)));
typedef unsigned short u16;
typedef unsigned int u32;

#define SCALE 0.0625f
#define MFMA32(a, b, c) __builtin_amdgcn_mfma_f32_16x16x32_bf16((a), (b), (c), 0, 0, 0)

__device__ inline u16 f2bf(float x) {
  u32 u = __float_as_uint(x);
  u32 r = u + 0x7FFFu + ((u >> 16) & 1u);
  return (u16)(r >> 16);
}
__device__ inline float bf2f(u16 h) { return __uint_as_float(((u32)h) << 16); }

// async global->LDS, 16B per lane; LDS dest is wave-uniform base + lane*16
__device__ __forceinline__ void gld16(const void* g, void* l) {
  __builtin_amdgcn_global_load_lds(
      (const __attribute__((address_space(1))) unsigned int*)(uintptr_t)g,
      (__attribute__((address_space(3))) unsigned int*)(uintptr_t)l, 16, 0, 0);
}

// ---------------------------------------------------------------------------
// Transpose+split W matrices: W[k][n] fp32 -> Wt_hi/lo[n][k] bf16.
// ---------------------------------------------------------------------------
__global__ __launch_bounds__(256) void convert_w(
    const float* __restrict__ Wq, const float* __restrict__ Wk, const float* __restrict__ Wv,
    u16* __restrict__ qh, u16* __restrict__ qlo2, u16* __restrict__ kh, u16* __restrict__ klo2,
    u16* __restrict__ vh, u16* __restrict__ vlo2) {
  int idx = blockIdx.x * 256 + threadIdx.x;
  const float* src;
  u16 *dh, *dl;
  int KD;
  const int nq = 416 * 256;
  if (idx < nq) {
    src = Wq; dh = qh; dl = qlo2; KD = 416;
  } else if (idx < 2 * nq) {
    idx -= nq; src = Wk; dh = kh; dl = klo2; KD = 416;
  } else {
    idx -= 2 * nq;
    if (idx >= 384 * 256) return;
    src = Wv; dh = vh; dl = vlo2; KD = 384;
  }
  int k = idx >> 8, n = idx & 255;
  float x = src[idx];
  u16 h = f2bf(x);
  dh[n * KD + k] = h;
  dl[n * KD + k] = f2bf(x - bf2f(h));
}

// ---------------------------------------------------------------------------
// Projection GEMM, split-bf16 MFMA: C[m][256] = A[m][KD] @ W[KD][256].
// OUT=0: flat hi/lo [m][256] (Q).
// OUT=1: K into kvswz per-(km,kt32) 32768-u16 block:
//        Kh slot = row*256 + (((c + 4*row)&31)<<3) + e   (row=j&31, c=d>>3, e=d&7)
//        Kl at +8192 u16.
// OUT=2: V into same block at +16384 u16:
//        Vh slot = 16384 + (d>>5)*1024 + (d&31)*32 + (j>>3)*8 + (j&7); Vl +8192.
// ---------------------------------------------------------------------------
template <int KD, int OUT>
__global__ __launch_bounds__(256, 3) void proj_mfma(
    const float* __restrict__ A, const u16* __restrict__ wth, const u16* __restrict__ wtl,
    u16* __restrict__ oh, u16* __restrict__ ol) {
  __shared__ u16 Ah[64 * 32], Al[64 * 32];
  __shared__ u16 Wh[256 * 32], Wl[256 * 32];
  const int t = threadIdx.x;
  const int w = t >> 6, l = t & 63;
  const int lr = l & 15, lk = l >> 4;
  const int m0 = blockIdx.x * 64;
  f32x4 acc[16];
#pragma unroll
  for (int i = 0; i < 16; ++i) acc[i] = {};
  const int arow = t >> 2, ac = t & 3;
  const int acp = (ac + (arow >> 1)) & 3;
  for (int k0 = 0; k0 < KD; k0 += 32) {
    __syncthreads();
    {
      const float* s1 = A + (size_t)(m0 + arow) * KD + k0 + ac * 8;
      float4 f1 = *(const float4*)s1;
      float4 f2 = *(const float4*)(s1 + 4);
      float fs[8] = {f1.x, f1.y, f1.z, f1.w, f2.x, f2.y, f2.z, f2.w};
      bf16x8 hv, lv;
#pragma unroll
      for (int j = 0; j < 8; ++j) {
        u16 h = f2bf(fs[j]);
        hv[j] = (short)h;
        lv[j] = (short)f2bf(fs[j] - bf2f(h));
      }
      *(bf16x8*)(Ah + arow * 32 + acp * 8) = hv;
      *(bf16x8*)(Al + arow * 32 + acp * 8) = lv;
#pragma unroll
      for (int i = 0; i < 4; ++i) {
        int ch = t + i * 256;
        int n = ch >> 2, c = ch & 3;
        int cp = (c + (n >> 1)) & 3;
        *(bf16x8*)(Wh + n * 32 + cp * 8) = *(const bf16x8*)(wth + (size_t)n * KD + k0 + c * 8);
        *(bf16x8*)(Wl + n * 32 + cp * 8) = *(const bf16x8*)(wtl + (size_t)n * KD + k0 + c * 8);
      }
    }
    __syncthreads();
    const int row = w * 16 + lr;
    const int rcp = (lk + (row >> 1)) & 3;
    bf16x8 ah = *(const bf16x8*)(Ah + row * 32 + rcp * 8);
    bf16x8 al = *(const bf16x8*)(Al + row * 32 + rcp * 8);
#pragma unroll
    for (int fc = 0; fc < 16; ++fc) {
      int n = lr + 16 * fc;
      int cp = (lk + (n >> 1)) & 3;
      bf16x8 bh = *(const bf16x8*)(Wh + n * 32 + cp * 8);
      bf16x8 bl = *(const bf16x8*)(Wl + n * 32 + cp * 8);
      acc[fc] = MFMA32(ah, bh, acc[fc]);
      acc[fc] = MFMA32(ah, bl, acc[fc]);
      acc[fc] = MFMA32(al, bh, acc[fc]);
    }
  }
  if (OUT == 0) {
#pragma unroll
    for (int fc = 0; fc < 16; ++fc) {
      int n = lr + 16 * fc;
#pragma unroll
      for (int r = 0; r < 4; ++r) {
        int m = m0 + w * 16 + lk * 4 + r;
        float v = acc[fc][r];
        u16 h = f2bf(v);
        oh[(size_t)m * 256 + n] = h;
        ol[(size_t)m * 256 + n] = f2bf(v - bf2f(h));
      }
    }
  } else if (OUT == 1) {
#pragma unroll
    for (int r = 0; r < 4; ++r) {
      int m = m0 + w * 16 + lk * 4 + r;
      int km = m / 576;
      int j = m - km * 576;
      int kt = j >> 5, row = j & 31;
      size_t rowbase = ((size_t)(km * 18 + kt) << 15) + (row << 8);
#pragma unroll
      for (int fc = 0; fc < 16; ++fc) {
        int c = (lr >> 3) + 2 * fc;
        size_t slot = rowbase + (size_t)((((c + 4 * row) & 31) << 3) + (lr & 7));
        float v = acc[fc][r];
        u16 h = f2bf(v);
        oh[slot] = h;
        oh[slot + 8192] = f2bf(v - bf2f(h));
      }
    }
  } else {
    const int km = m0 / 576;
    const int j0 = (m0 % 576) + w * 16 + lk * 4;
    const int kt = j0 >> 5;
    const int j0l = j0 & 31;
    const int cc = j0l >> 3, ee = j0l & 7;
    const size_t vbase = ((size_t)(km * 18 + kt) << 15) + 16384;
#pragma unroll
    for (int fc = 0; fc < 16; ++fc) {
      // d = lr + 16*fc -> slice w = fc>>1, r = lr + (fc&1)*16
      size_t slot = vbase + (size_t)((fc >> 1) * 1024 + (lr + (fc & 1) * 16) * 32 + cc * 8 + ee);
      u16 hs[4], ls[4];
#pragma unroll
      for (int r = 0; r < 4; ++r) {
        float v = acc[fc][r];
        u16 h = f2bf(v);
        hs[r] = h;
        ls[r] = f2bf(v - bf2f(h));
      }
      *(ushort4*)(oh + slot) = make_ushort4(hs[0], hs[1], hs[2], hs[3]);
      *(ushort4*)(oh + slot + 8192) = make_ushort4(ls[0], ls[1], ls[2], ls[3]);
    }
  }
}

// ---------------------------------------------------------------------------
// Flash attention (r6 geometry + pipelined schedule):
// 512 thr / 8 waves = (wq 0..3) x (wk 0..1); block = 64 q x 32 keys/kt.
// Swapped QK^T (S^T = mfma(K,Q)), 3 parallel accumulators; P hi/lo via LDS
// (b64 stores); PV d-split (wave w owns d = w*32..+31) with SELF-SLICED V
// staging so V residency/refill needs no barrier.  2 barriers per kt,
// counted vmcnt only.  m==0 softmax, stats reduced once at end.
// R written [b,km][d][n] normalized.
// ---------------------------------------------------------------------------
__global__ __launch_bounds__(512, 4) void attn_kernel(
    const u16* __restrict__ qhi, const u16* __restrict__ qlo,
    const u16* __restrict__ kvswz,
    float* __restrict__ rpartT, float* __restrict__ invl) {
  __shared__ u16 KV[32768];  // u16: [Kh 8192][Kl 8192][Vh 8192][Vl 8192]
  __shared__ u16 Ph[64 * 40], Pl[64 * 40];
  __shared__ float lred[2][64], mred[2][64];
  __shared__ float invs[64];
  const int t = threadIdx.x;
  const int w = t >> 6, l = t & 63;
  const int lr = l & 15, lk = l >> 4;
  const int wq = w >> 1, wk = w & 1;
  // XCD-cluster swizzle: all 36 blocks of one km land on xcd = km%8.
  const int L = blockIdx.x;
  const int xcd = L & 7, slot = L >> 3;
  const int km = xcd + 8 * (slot / 36);
  const int inner = slot % 36;
  const int b = inner & 3, qb = inner >> 2;
  const int qw = qb * 64 + wq * 16;

  // Q fragments (B-operand of swapped QK: col=q=lr, k-chunk lk*8 + s*32)
  bf16x8 qh[8], qlv[8];
  {
    const size_t qoff = ((size_t)(b * 576 + qw + lr)) * 256 + lk * 8;
#pragma unroll
    for (int s = 0; s < 8; ++s) {
      qh[s] = *(const bf16x8*)(qhi + qoff + s * 32);
      qlv[s] = *(const bf16x8*)(qlo + qoff + s * 32);
    }
  }

  f32x4 o[4][2];
#pragma unroll
  for (int i = 0; i < 4; ++i)
#pragma unroll
    for (int j = 0; j < 2; ++j) o[i][j] = {};
  float m_part = -1e30f, l_part = 0.f;  // per-lane, q = wq*16+lr (over wk half keys)

  const char* kvb = (const char*)kvswz + (size_t)(km * 18) * 65536;
  char* lds0 = (char*)&KV[0];

  auto STAGE_K = [&](int kt) {
    const char* src = kvb + (size_t)kt * 65536 + t * 16;
    char* dst = lds0 + t * 16;
#pragma unroll
    for (int rgn = 0; rgn < 4; ++rgn) gld16(src + rgn * 8192, dst + rgn * 8192);
  };
  auto STAGE_V = [&](int kt) {
    // wave-self slice: Vh bytes 32768 + w*2048 (+16384 for Vl)
    const char* src = kvb + (size_t)kt * 65536 + w * 2048 + l * 16;
    char* dst = lds0 + w * 2048 + l * 16;
#pragma unroll
    for (int c = 0; c < 2; ++c) {
      gld16(src + 32768 + c * 1024, dst + 32768 + c * 1024);
      gld16(src + 49152 + c * 1024, dst + 49152 + c * 1024);
    }
  };

  // prologue
  asm volatile("s_waitcnt vmcnt(0)" ::: "memory");  // Q drained: clean FIFO
  __builtin_amdgcn_sched_barrier(0);
  STAGE_K(0);
  __builtin_amdgcn_sched_barrier(0);
  STAGE_V(0);
  asm volatile("s_waitcnt vmcnt(4)" ::: "memory");  // my K(0) landed
  __builtin_amdgcn_sched_barrier(0);
  __builtin_amdgcn_s_barrier();  // all K(0) landed
  __builtin_amdgcn_sched_barrier(0);

  const int krow = wk * 16 + lr;

  for (int kt = 0; kt < 18; ++kt) {
    // ---- QK^T: A = K-frag (keys wk*16..+15), B = Q; 3 parallel accumulators
    f32x4 sA = {}, sB = {}, sC = {};
    __builtin_amdgcn_s_setprio(1);
#pragma unroll
    for (int s = 0; s < 8; ++s) {
      const int c = (((s * 4 + lk) + 4 * krow) & 31) * 8;
      bf16x8 khf = *(const bf16x8*)(KV + krow * 256 + c);
      bf16x8 klf = *(const bf16x8*)(KV + 8192 + krow * 256 + c);
      sA = MFMA32(khf, qh[s], sA);
      sB = MFMA32(klf, qh[s], sB);
      sC = MFMA32(khf, qlv[s], sC);
    }
    __builtin_amdgcn_s_setprio(0);

    // ---- P = exp(S*scale): lane holds keys wk*16 + lk*4..+3, q = wq*16+lr
    ushort4 ph4, pl4;
#pragma unroll
    for (int r = 0; r < 4; ++r) {
      float a = (sA[r] + sB[r] + sC[r]) * SCALE;
      m_part = fmaxf(m_part, a);
      float e = __expf(a);
      l_part += e;
      u16 h = f2bf(e);
      (&ph4.x)[r] = h;
      (&pl4.x)[r] = f2bf(e - bf2f(h));
    }
    {
      int poff = (wq * 16 + lr) * 40 + wk * 16 + lk * 4;
      *(ushort4*)(Ph + poff) = ph4;
      *(ushort4*)(Pl + poff) = pl4;
    }
    asm volatile("s_waitcnt lgkmcnt(0)" ::: "memory");  // K reads + P write done
    __builtin_amdgcn_sched_barrier(0);
    __builtin_amdgcn_s_barrier();  // B1: P visible, K region free
    __builtin_amdgcn_sched_barrier(0);

    const int ktn = kt < 17 ? kt + 1 : 17;
    STAGE_K(ktn);  // flies under PV
    __builtin_amdgcn_sched_barrier(0);
    asm volatile("s_waitcnt vmcnt(4)" ::: "memory");  // my V(kt) landed
    __builtin_amdgcn_sched_barrier(0);

    // ---- hoist my V frags to regs (only reads of V region this kt)
    bf16x8 vhf[2], vlf[2];
#pragma unroll
    for (int dt = 0; dt < 2; ++dt) {
      vhf[dt] = *(const bf16x8*)(KV + 16384 + w * 1024 + (dt * 16 + lr) * 32 + lk * 8);
      vlf[dt] = *(const bf16x8*)(KV + 24576 + w * 1024 + (dt * 16 + lr) * 32 + lk * 8);
    }
    asm volatile("s_waitcnt lgkmcnt(0)" ::: "memory");  // V frag reads done
    __builtin_amdgcn_sched_barrier(0);
    STAGE_V(ktn);  // safe: only this wave reads its V slice
    __builtin_amdgcn_sched_barrier(0);

    // ---- PV: wave covers d = w*32 + dt*16 + lr for all 64 q
    __builtin_amdgcn_s_setprio(1);
#pragma unroll
    for (int qt = 0; qt < 4; ++qt) {
      bf16x8 pah = *(const bf16x8*)(Ph + (qt * 16 + lr) * 40 + lk * 8);
      bf16x8 pal = *(const bf16x8*)(Pl + (qt * 16 + lr) * 40 + lk * 8);
#pragma unroll
      for (int dt = 0; dt < 2; ++dt) {
        o[qt][dt] = MFMA32(pah, vhf[dt], o[qt][dt]);
        o[qt][dt] = MFMA32(pah, vlf[dt], o[qt][dt]);
        o[qt][dt] = MFMA32(pal, vhf[dt], o[qt][dt]);
      }
    }
    __builtin_amdgcn_s_setprio(0);
    asm volatile("s_waitcnt vmcnt(4)" ::: "memory");  // my K(kt+1) landed
    __builtin_amdgcn_sched_barrier(0);
    asm volatile("s_waitcnt lgkmcnt(0)" ::: "memory");  // my P reads done
    __builtin_amdgcn_sched_barrier(0);
    __builtin_amdgcn_s_barrier();  // B2: all K landed, P region free
    __builtin_amdgcn_sched_barrier(0);
  }

  // ---- stats: lane q=wq*16+lr; combine lk groups then wk halves
  {
    float lv = l_part, mv = m_part;
    lv += __shfl_xor(lv, 16, 64);
    mv = fmaxf(mv, __shfl_xor(mv, 16, 64));
    lv += __shfl_xor(lv, 32, 64);
    mv = fmaxf(mv, __shfl_xor(mv, 32, 64));
    if (l < 16) {
      lred[wk][wq * 16 + l] = lv;
      mred[wk][wq * 16 + l] = mv;
    }
  }
  __syncthreads();
  if (w == 0) {
    float ls = lred[0][l] + lred[1][l];
    float mv = fmaxf(mred[0][l], mred[1][l]);
    invs[l] = 1.0f / ls;
    invl[(size_t)(b * 80 + km) * 576 + qb * 64 + l] = __expf(mv) / ls;
  }
  __syncthreads();

  float* dst = rpartT + (size_t)(b * 80 + km) * 147456;
#pragma unroll
  for (int qt = 0; qt < 4; ++qt) {
    float iv[4];
#pragma unroll
    for (int r = 0; r < 4; ++r) iv[r] = invs[qt * 16 + lk * 4 + r];
#pragma unroll
    for (int dt = 0; dt < 2; ++dt) {
      int d = w * 32 + dt * 16 + lr;
      f32x4 vv;
      vv[0] = o[qt][dt][0] * iv[0];
      vv[1] = o[qt][dt][1] * iv[1];
      vv[2] = o[qt][dt][2] * iv[2];
      vv[3] = o[qt][dt][3] * iv[3];
      *(f32x4*)(dst + (size_t)d * 576 + qb * 64 + qt * 16 + lk * 4) = vv;
    }
  }
}

// ---------------------------------------------------------------------------
// Weights: s[b,k,m] = mean_n 1/l_ref ; w = gate(p) * s / (sum_m s + 1e-8)
// ---------------------------------------------------------------------------
__global__ __launch_bounds__(256) void weight_kernel(const float* __restrict__ invl,
                                                     const float* __restrict__ p,
                                                     float* __restrict__ wout) {
  const int k = blockIdx.x, b = blockIdx.y;
  __shared__ float sm[10];
  __shared__ float red[4];
  const int t = threadIdx.x;
  for (int m = 0; m < 10; ++m) {
    float part = 0.f;
    for (int n = t; n < 576; n += 256)
      part += invl[(size_t)((b * 8 + k) * 10 + m) * 576 + n];
#pragma unroll
    for (int off = 32; off; off >>= 1) part += __shfl_down(part, off, 64);
    if ((t & 63) == 0) red[t >> 6] = part;
    __syncthreads();
    if (t == 0) sm[m] = (red[0] + red[1] + red[2] + red[3]) * (1.0f / 576.0f);
    __syncthreads();
  }
  if (t == 0) {
    float tot = 0.f;
    for (int m = 0; m < 10; ++m) tot += sm[m];
    float pmax = fmaxf(fmaxf(p[0 * 8 + k], p[1 * 8 + k]), fmaxf(p[2 * 8 + k], p[3 * 8 + k]));
    float gate = (pmax >= 0.01f) ? p[b * 8 + k] : 0.0f;
    for (int m = 0; m < 10; ++m)
      wout[(b * 8 + k) * 10 + m] = gate * sm[m] / (tot + 1e-8f);
  }
}

// ---------------------------------------------------------------------------
// out[b][d][n] = sum_km w[b,km] * rpartT[b,km][d][n]
// ---------------------------------------------------------------------------
__global__ __launch_bounds__(256) void reduce_out_k(const float* __restrict__ rpartT,
                                                    const float* __restrict__ wbuf,
                                                    float* __restrict__ out) {
  int idx = blockIdx.x * 256 + threadIdx.x;
  int b = idx / 147456;
  size_t off = (size_t)(idx % 147456);
  const float* base = rpartT + (size_t)b * 80 * 147456 + off;
  const float* wp = wbuf + b * 80;
  float acc = 0.f;
#pragma unroll 8
  for (int g = 0; g < 80; ++g) acc += wp[g] * base[(size_t)g * 147456];
  out[idx] = acc;
}

// ---------------------------------------------------------------------------
extern "C" void kernel_launch(void* const* d_in, const int* in_sizes, int n_in,
                              void* d_out, int out_size, void* d_ws, size_t ws_size,
                              hipStream_t stream) {
  const float* Q = (const float*)d_in[0];
  const float* dbk = (const float*)d_in[1];
  const float* dbv = (const float*)d_in[2];
  const float* p = (const float*)d_in[3];
  const float* Wq = (const float*)d_in[4];
  const float* Wk = (const float*)d_in[5];
  const float* Wv = (const float*)d_in[6];
  float* out = (float*)d_out;
  char* ws = (char*)d_ws;

  u16* qhi = (u16*)(ws);                    // 1,179,648 B
  u16* qlo = (u16*)(ws + 1179648);          // 1,179,648 B
  u16* kvswz = (u16*)(ws + 2359296);        // 80*18*65536 = 94,371,840 B
  float* invl = (float*)(ws + 96731136);    // 737,280 B
  float* wbuf = (float*)(ws + 97468416);    // 1,280 B
  float* rpartT = (float*)(ws + 97469696);  // 188,743,680 B
  // W^T hi/lo temporaries aliased into rpartT region (consumed before attn writes)
  u16* wqh = (u16*)(ws + 97469696);
  u16* wql = wqh + 106496;
  u16* wkh = wql + 106496;
  u16* wkl = wkh + 106496;
  u16* wvh = wkl + 106496;
  u16* wvl = wvh + 98304;

  convert_w<<<1216, 256, 0, stream>>>(Wq, Wk, Wv, wqh, wql, wkh, wkl, wvh, wvl);
  proj_mfma<416, 0><<<36, 256, 0, stream>>>(Q, wqh, wql, qhi, qlo);
  proj_mfma<416, 1><<<720, 256, 0, stream>>>(dbk, wkh, wkl, kvswz, nullptr);
  proj_mfma<384, 2><<<720, 256, 0, stream>>>(dbv, wvh, wvl, kvswz, nullptr);
  attn_kernel<<<2880, 512, 0, stream>>>(qhi, qlo, kvswz, rpartT, invl);
  weight_kernel<<<dim3(8, 4), 256, 0, stream>>>(invl, p, wbuf);
  reduce_out_k<<<2304, 256, 0, stream>>>(rpartT, wbuf, out);
}

// Round 9
// 486.795 us; speedup vs baseline: 2.2372x; 1.5433x over previous
//
#include <hip/hip_runtime.h>

typedef float f32x4 __attribute__((ext_vector_type(4)));
typedef short bf16x8 __attribute__((ext_vector_type(8)));
typedef unsigned short u16;
typedef unsigned int u32;

#define SCALE 0.0625f
#define MFMA32(a, b, c) __builtin_amdgcn_mfma_f32_16x16x32_bf16((a), (b), (c), 0, 0, 0)

__device__ inline u16 f2bf(float x) {
  u32 u = __float_as_uint(x);
  u32 r = u + 0x7FFFu + ((u >> 16) & 1u);
  return (u16)(r >> 16);
}
__device__ inline float bf2f(u16 h) { return __uint_as_float(((u32)h) << 16); }

// async global->LDS, 16B per lane; LDS dest is wave-uniform base + lane*16
__device__ __forceinline__ void gld16(const void* g, void* l) {
  __builtin_amdgcn_global_load_lds(
      (const __attribute__((address_space(1))) unsigned int*)(uintptr_t)g,
      (__attribute__((address_space(3))) unsigned int*)(uintptr_t)l, 16, 0, 0);
}

// ---------------------------------------------------------------------------
// Transpose+split W matrices: W[k][n] fp32 -> Wt_hi/lo[n][k] bf16.
// ---------------------------------------------------------------------------
__global__ __launch_bounds__(256) void convert_w(
    const float* __restrict__ Wq, const float* __restrict__ Wk, const float* __restrict__ Wv,
    u16* __restrict__ qh, u16* __restrict__ qlo2, u16* __restrict__ kh, u16* __restrict__ klo2,
    u16* __restrict__ vh, u16* __restrict__ vlo2) {
  int idx = blockIdx.x * 256 + threadIdx.x;
  const float* src;
  u16 *dh, *dl;
  int KD;
  const int nq = 416 * 256;
  if (idx < nq) {
    src = Wq; dh = qh; dl = qlo2; KD = 416;
  } else if (idx < 2 * nq) {
    idx -= nq; src = Wk; dh = kh; dl = klo2; KD = 416;
  } else {
    idx -= 2 * nq;
    if (idx >= 384 * 256) return;
    src = Wv; dh = vh; dl = vlo2; KD = 384;
  }
  int k = idx >> 8, n = idx & 255;
  float x = src[idx];
  u16 h = f2bf(x);
  dh[n * KD + k] = h;
  dl[n * KD + k] = f2bf(x - bf2f(h));
}

// ---------------------------------------------------------------------------
// Projection GEMM, split-bf16 MFMA: C[m][256] = A[m][KD] @ W[KD][256].
// OUT=0: flat hi/lo [m][256] (Q).
// OUT=1: K (hi only) into kvswz per-(km,kt32) 16384-u16 block:
//        slot = row*256 + (((c + 5*row)&31)<<3) + e   (row=j&31, c=d>>3, e=d&7)
// OUT=2: V (hi only) at +8192 u16: per-wave(d>>5) region 1024 u16, chunk-major:
//        slot = 8192 + (d>>5)*1024 + ((((j&31)>>3)*32 + (d&31))<<3) + (j&7)
// ---------------------------------------------------------------------------
template <int KD, int OUT>
__global__ __launch_bounds__(256, 3) void proj_mfma(
    const float* __restrict__ A, const u16* __restrict__ wth, const u16* __restrict__ wtl,
    u16* __restrict__ oh, u16* __restrict__ ol) {
  __shared__ u16 Ah[64 * 32], Al[64 * 32];
  __shared__ u16 Wh[256 * 32], Wl[256 * 32];
  const int t = threadIdx.x;
  const int w = t >> 6, l = t & 63;
  const int lr = l & 15, lk = l >> 4;
  const int m0 = blockIdx.x * 64;
  f32x4 acc[16];
#pragma unroll
  for (int i = 0; i < 16; ++i) acc[i] = {};
  const int arow = t >> 2, ac = t & 3;
  const int acp = (ac + (arow >> 1)) & 3;
  for (int k0 = 0; k0 < KD; k0 += 32) {
    __syncthreads();
    {
      const float* s1 = A + (size_t)(m0 + arow) * KD + k0 + ac * 8;
      float4 f1 = *(const float4*)s1;
      float4 f2 = *(const float4*)(s1 + 4);
      float fs[8] = {f1.x, f1.y, f1.z, f1.w, f2.x, f2.y, f2.z, f2.w};
      bf16x8 hv, lv;
#pragma unroll
      for (int j = 0; j < 8; ++j) {
        u16 h = f2bf(fs[j]);
        hv[j] = (short)h;
        lv[j] = (short)f2bf(fs[j] - bf2f(h));
      }
      *(bf16x8*)(Ah + arow * 32 + acp * 8) = hv;
      *(bf16x8*)(Al + arow * 32 + acp * 8) = lv;
#pragma unroll
      for (int i = 0; i < 4; ++i) {
        int ch = t + i * 256;
        int n = ch >> 2, c = ch & 3;
        int cp = (c + (n >> 1)) & 3;
        *(bf16x8*)(Wh + n * 32 + cp * 8) = *(const bf16x8*)(wth + (size_t)n * KD + k0 + c * 8);
        *(bf16x8*)(Wl + n * 32 + cp * 8) = *(const bf16x8*)(wtl + (size_t)n * KD + k0 + c * 8);
      }
    }
    __syncthreads();
    const int row = w * 16 + lr;
    const int rcp = (lk + (row >> 1)) & 3;
    bf16x8 ah = *(const bf16x8*)(Ah + row * 32 + rcp * 8);
    bf16x8 al = *(const bf16x8*)(Al + row * 32 + rcp * 8);
#pragma unroll
    for (int fc = 0; fc < 16; ++fc) {
      int n = lr + 16 * fc;
      int cp = (lk + (n >> 1)) & 3;
      bf16x8 bh = *(const bf16x8*)(Wh + n * 32 + cp * 8);
      bf16x8 bl = *(const bf16x8*)(Wl + n * 32 + cp * 8);
      acc[fc] = MFMA32(ah, bh, acc[fc]);
      acc[fc] = MFMA32(ah, bl, acc[fc]);
      acc[fc] = MFMA32(al, bh, acc[fc]);
    }
  }
  if (OUT == 0) {
#pragma unroll
    for (int fc = 0; fc < 16; ++fc) {
      int n = lr + 16 * fc;
#pragma unroll
      for (int r = 0; r < 4; ++r) {
        int m = m0 + w * 16 + lk * 4 + r;
        float v = acc[fc][r];
        u16 h = f2bf(v);
        oh[(size_t)m * 256 + n] = h;
        ol[(size_t)m * 256 + n] = f2bf(v - bf2f(h));
      }
    }
  } else if (OUT == 1) {
#pragma unroll
    for (int r = 0; r < 4; ++r) {
      int m = m0 + w * 16 + lk * 4 + r;
      int km = m / 576;
      int j = m - km * 576;
      int kt = j >> 5, row = j & 31;
      size_t rowbase = (size_t)(km * 18 + kt) * 16384 + (row << 8);
#pragma unroll
      for (int fc = 0; fc < 16; ++fc) {
        int c = (lr >> 3) + 2 * fc;
        size_t slot = rowbase + (size_t)((((c + 5 * row) & 31) << 3) + (lr & 7));
        oh[slot] = f2bf(acc[fc][r]);
      }
    }
  } else {
    const int km = m0 / 576;
    const int j0 = (m0 % 576) + w * 16 + lk * 4;
    const int kt = j0 >> 5;
    const int jl = j0 & 31;
    const int ck = jl >> 3, e0 = jl & 7;
    const size_t vbase = (size_t)(km * 18 + kt) * 16384 + 8192;
#pragma unroll
    for (int fc = 0; fc < 16; ++fc) {
      // d = lr + 16*fc -> region fc>>1, rr = lr + (fc&1)*16
      size_t slot = vbase + (size_t)((fc >> 1) * 1024 + ((ck * 32 + lr + (fc & 1) * 16) << 3) + e0);
      u16 hs[4];
#pragma unroll
      for (int r = 0; r < 4; ++r) hs[r] = f2bf(acc[fc][r]);
      *(ushort4*)(oh + slot) = make_ushort4(hs[0], hs[1], hs[2], hs[3]);
    }
  }
}

// ---------------------------------------------------------------------------
// Flash attention: 512 thr / 8 waves = (wq 0..3) x (wk 0..1); 64 q x 32 keys/kt.
// Precision: S = (qh+ql)*kh (K-lo dropped); PV = ph*vh (P-lo, V-lo dropped).
// Per wave-kt: 8 K-reads + 16 MFMA (QK), 1 P b64 write, 4 P-reads + 2 V-reads
// + 8 MFMA (PV), 4 staging DMAs.  Odd-multiplier swizzles -> conflict-free
// phases.  2 barriers/kt, counted vmcnt only.  m==0 softmax.
// ---------------------------------------------------------------------------
__global__ __launch_bounds__(512, 4) void attn_kernel(
    const u16* __restrict__ qhi, const u16* __restrict__ qlo,
    const u16* __restrict__ kvswz,
    float* __restrict__ rpartT, float* __restrict__ invl) {
  __shared__ u16 KV[16384];  // u16: [Kh 8192][Vh 8192]
  __shared__ u16 Ph[64 * 40];
  __shared__ float lred[2][64], mred[2][64];
  __shared__ float invs[64];
  const int t = threadIdx.x;
  const int w = t >> 6, l = t & 63;
  const int lr = l & 15, lk = l >> 4;
  const int wq = w >> 1, wk = w & 1;
  // XCD-cluster swizzle: all 36 blocks of one km land on xcd = km%8.
  const int L = blockIdx.x;
  const int xcd = L & 7, slot = L >> 3;
  const int km = xcd + 8 * (slot / 36);
  const int inner = slot % 36;
  const int b = inner & 3, qb = inner >> 2;
  const int qw = qb * 64 + wq * 16;

  // Q fragments (B-operand of swapped QK: col=q=lr, k-chunk lk*8 + s*32)
  bf16x8 qh[8], qlv[8];
  {
    const size_t qoff = ((size_t)(b * 576 + qw + lr)) * 256 + lk * 8;
#pragma unroll
    for (int s = 0; s < 8; ++s) {
      qh[s] = *(const bf16x8*)(qhi + qoff + s * 32);
      qlv[s] = *(const bf16x8*)(qlo + qoff + s * 32);
    }
  }

  f32x4 o[4][2];
#pragma unroll
  for (int i = 0; i < 4; ++i)
#pragma unroll
    for (int j = 0; j < 2; ++j) o[i][j] = {};
  float m_part = -1e30f, l_part = 0.f;  // per-lane: q=wq*16+lr, keys wk*16+lk*4..+3

  const char* kvb = (const char*)kvswz + (size_t)(km * 18) * 32768;
  char* lds0 = (char*)&KV[0];

  auto STAGE_K = [&](int kt) {
    const char* src = kvb + (size_t)kt * 32768 + t * 16;
    char* dst = lds0 + t * 16;
    gld16(src, dst);
    gld16(src + 8192, dst + 8192);
  };
  auto STAGE_V = [&](int kt) {
    // wave-self slice: bytes 16384 + w*2048 .. +2048
    const char* src = kvb + (size_t)kt * 32768 + 16384 + w * 2048 + l * 16;
    char* dst = lds0 + 16384 + w * 2048 + l * 16;
    gld16(src, dst);
    gld16(src + 1024, dst + 1024);
  };

  // prologue
  asm volatile("s_waitcnt vmcnt(0)" ::: "memory");  // Q drained: clean FIFO
  __builtin_amdgcn_sched_barrier(0);
  STAGE_K(0);
  __builtin_amdgcn_sched_barrier(0);
  STAGE_V(0);
  asm volatile("s_waitcnt vmcnt(2)" ::: "memory");  // my K(0) landed, V(0) in flight
  __builtin_amdgcn_sched_barrier(0);
  __builtin_amdgcn_s_barrier();  // all K(0) landed
  __builtin_amdgcn_sched_barrier(0);

  const int krow = wk * 16 + lr;

  for (int kt = 0; kt < 18; ++kt) {
    // ---- QK^T: A = K-frag (keys wk*16..+15), B = Q; 2 parallel accumulators
    f32x4 sA = {}, sB = {};
    __builtin_amdgcn_s_setprio(1);
#pragma unroll
    for (int s = 0; s < 8; ++s) {
      const int cc = ((s * 4 + lk) + 5 * krow) & 31;
      bf16x8 khf = *(const bf16x8*)(KV + krow * 256 + cc * 8);
      sA = MFMA32(khf, qh[s], sA);
      sB = MFMA32(khf, qlv[s], sB);
    }
    __builtin_amdgcn_s_setprio(0);

    // ---- P = exp(S*scale): lane holds keys wk*16 + lk*4..+3, q = wq*16+lr
    ushort4 ph4;
#pragma unroll
    for (int r = 0; r < 4; ++r) {
      float a = (sA[r] + sB[r]) * SCALE;
      m_part = fmaxf(m_part, a);
      float e = __expf(a);
      l_part += e;
      (&ph4.x)[r] = f2bf(e);
    }
    *(ushort4*)(Ph + (wq * 16 + lr) * 40 + wk * 16 + lk * 4) = ph4;
    asm volatile("s_waitcnt lgkmcnt(0)" ::: "memory");  // K reads + P write done
    __builtin_amdgcn_sched_barrier(0);
    __builtin_amdgcn_s_barrier();  // B1: P visible, K region free
    __builtin_amdgcn_sched_barrier(0);

    const int ktn = kt < 17 ? kt + 1 : 17;
    STAGE_K(ktn);  // flies under PV
    __builtin_amdgcn_sched_barrier(0);
    asm volatile("s_waitcnt vmcnt(2)" ::: "memory");  // my V(kt) landed
    __builtin_amdgcn_sched_barrier(0);

    // ---- hoist my V frags to regs (only reads of my V slice this kt)
    bf16x8 vhf[2];
#pragma unroll
    for (int dt = 0; dt < 2; ++dt)
      vhf[dt] = *(const bf16x8*)(KV + 8192 + w * 1024 + (lk * 32 + dt * 16 + lr) * 8);
    asm volatile("s_waitcnt lgkmcnt(0)" ::: "memory");  // V frag reads done
    __builtin_amdgcn_sched_barrier(0);
    STAGE_V(ktn);  // safe: only this wave reads its V slice
    __builtin_amdgcn_sched_barrier(0);

    // ---- PV: wave covers d = w*32 + dt*16 + lr for all 64 q
    __builtin_amdgcn_s_setprio(1);
#pragma unroll
    for (int qt = 0; qt < 4; ++qt) {
      bf16x8 pah = *(const bf16x8*)(Ph + (qt * 16 + lr) * 40 + lk * 8);
#pragma unroll
      for (int dt = 0; dt < 2; ++dt)
        o[qt][dt] = MFMA32(pah, vhf[dt], o[qt][dt]);
    }
    __builtin_amdgcn_s_setprio(0);
    asm volatile("s_waitcnt vmcnt(2)" ::: "memory");  // my K(kt+1) landed
    __builtin_amdgcn_sched_barrier(0);
    asm volatile("s_waitcnt lgkmcnt(0)" ::: "memory");  // my P reads done
    __builtin_amdgcn_sched_barrier(0);
    __builtin_amdgcn_s_barrier();  // B2: all K landed, P region free
    __builtin_amdgcn_sched_barrier(0);
  }

  // ---- stats: lane q=wq*16+lr; combine lk groups then wk halves
  {
    float lv = l_part, mv = m_part;
    lv += __shfl_xor(lv, 16, 64);
    mv = fmaxf(mv, __shfl_xor(mv, 16, 64));
    lv += __shfl_xor(lv, 32, 64);
    mv = fmaxf(mv, __shfl_xor(mv, 32, 64));
    if (l < 16) {
      lred[wk][wq * 16 + l] = lv;
      mred[wk][wq * 16 + l] = mv;
    }
  }
  __syncthreads();
  if (w == 0) {
    float ls = lred[0][l] + lred[1][l];
    float mv = fmaxf(mred[0][l], mred[1][l]);
    invs[l] = 1.0f / ls;
    invl[(size_t)(b * 80 + km) * 576 + qb * 64 + l] = __expf(mv) / ls;
  }
  __syncthreads();

  float* dst = rpartT + (size_t)(b * 80 + km) * 147456;
#pragma unroll
  for (int qt = 0; qt < 4; ++qt) {
    float iv[4];
#pragma unroll
    for (int r = 0; r < 4; ++r) iv[r] = invs[qt * 16 + lk * 4 + r];
#pragma unroll
    for (int dt = 0; dt < 2; ++dt) {
      int d = w * 32 + dt * 16 + lr;
      f32x4 vv;
      vv[0] = o[qt][dt][0] * iv[0];
      vv[1] = o[qt][dt][1] * iv[1];
      vv[2] = o[qt][dt][2] * iv[2];
      vv[3] = o[qt][dt][3] * iv[3];
      *(f32x4*)(dst + (size_t)d * 576 + qb * 64 + qt * 16 + lk * 4) = vv;
    }
  }
}

// ---------------------------------------------------------------------------
// Weights: s[b,k,m] = mean_n 1/l_ref ; w = gate(p) * s / (sum_m s + 1e-8)
// ---------------------------------------------------------------------------
__global__ __launch_bounds__(256) void weight_kernel(const float* __restrict__ invl,
                                                     const float* __restrict__ p,
                                                     float* __restrict__ wout) {
  const int k = blockIdx.x, b = blockIdx.y;
  __shared__ float sm[10];
  __shared__ float red[4];
  const int t = threadIdx.x;
  for (int m = 0; m < 10; ++m) {
    float part = 0.f;
    for (int n = t; n < 576; n += 256)
      part += invl[(size_t)((b * 8 + k) * 10 + m) * 576 + n];
#pragma unroll
    for (int off = 32; off; off >>= 1) part += __shfl_down(part, off, 64);
    if ((t & 63) == 0) red[t >> 6] = part;
    __syncthreads();
    if (t == 0) sm[m] = (red[0] + red[1] + red[2] + red[3]) * (1.0f / 576.0f);
    __syncthreads();
  }
  if (t == 0) {
    float tot = 0.f;
    for (int m = 0; m < 10; ++m) tot += sm[m];
    float pmax = fmaxf(fmaxf(p[0 * 8 + k], p[1 * 8 + k]), fmaxf(p[2 * 8 + k], p[3 * 8 + k]));
    float gate = (pmax >= 0.01f) ? p[b * 8 + k] : 0.0f;
    for (int m = 0; m < 10; ++m)
      wout[(b * 8 + k) * 10 + m] = gate * sm[m] / (tot + 1e-8f);
  }
}

// ---------------------------------------------------------------------------
// out[b][d][n] = sum_km w[b,km] * rpartT[b,km][d][n]
// ---------------------------------------------------------------------------
__global__ __launch_bounds__(256) void reduce_out_k(const float* __restrict__ rpartT,
                                                    const float* __restrict__ wbuf,
                                                    float* __restrict__ out) {
  int idx = blockIdx.x * 256 + threadIdx.x;
  int b = idx / 147456;
  size_t off = (size_t)(idx % 147456);
  const float* base = rpartT + (size_t)b * 80 * 147456 + off;
  const float* wp = wbuf + b * 80;
  float acc = 0.f;
#pragma unroll 8
  for (int g = 0; g < 80; ++g) acc += wp[g] * base[(size_t)g * 147456];
  out[idx] = acc;
}

// ---------------------------------------------------------------------------
extern "C" void kernel_launch(void* const* d_in, const int* in_sizes, int n_in,
                              void* d_out, int out_size, void* d_ws, size_t ws_size,
                              hipStream_t stream) {
  const float* Q = (const float*)d_in[0];
  const float* dbk = (const float*)d_in[1];
  const float* dbv = (const float*)d_in[2];
  const float* p = (const float*)d_in[3];
  const float* Wq = (const float*)d_in[4];
  const float* Wk = (const float*)d_in[5];
  const float* Wv = (const float*)d_in[6];
  float* out = (float*)d_out;
  char* ws = (char*)d_ws;

  u16* qhi = (u16*)(ws);                    // 1,179,648 B
  u16* qlo = (u16*)(ws + 1179648);          // 1,179,648 B
  u16* kvswz = (u16*)(ws + 2359296);        // 80*18*32768 = 47,185,920 B
  float* invl = (float*)(ws + 49545216);    // 737,280 B
  float* wbuf = (float*)(ws + 50282496);    // 1,280 B
  float* rpartT = (float*)(ws + 50283776);  // 188,743,680 B
  // W^T hi/lo temporaries aliased into rpartT region (consumed before attn writes)
  u16* wqh = (u16*)(ws + 50283776);
  u16* wql = wqh + 106496;
  u16* wkh = wql + 106496;
  u16* wkl = wkh + 106496;
  u16* wvh = wkl + 106496;
  u16* wvl = wvh + 98304;

  convert_w<<<1216, 256, 0, stream>>>(Wq, Wk, Wv, wqh, wql, wkh, wkl, wvh, wvl);
  proj_mfma<416, 0><<<36, 256, 0, stream>>>(Q, wqh, wql, qhi, qlo);
  proj_mfma<416, 1><<<720, 256, 0, stream>>>(dbk, wkh, wkl, kvswz, nullptr);
  proj_mfma<384, 2><<<720, 256, 0, stream>>>(dbv, wvh, wvl, kvswz, nullptr);
  attn_kernel<<<2880, 512, 0, stream>>>(qhi, qlo, kvswz, rpartT, invl);
  weight_kernel<<<dim3(8, 4), 256, 0, stream>>>(invl, p, wbuf);
  reduce_out_k<<<2304, 256, 0, stream>>>(rpartT, wbuf, out);
}

// Round 10
// 366.691 us; speedup vs baseline: 2.9700x; 1.3275x over previous
//
#include <hip/hip_runtime.h>

typedef float f32x4 __attribute__((ext_vector_type(4)));
typedef short bf16x8 __attribute__((ext_vector_type(8)));
typedef unsigned short u16;
typedef unsigned int u32;

#define SCALE 0.0625f
#define MFMA32(a, b, c) __builtin_amdgcn_mfma_f32_16x16x32_bf16((a), (b), (c), 0, 0, 0)

__device__ inline u16 f2bf(float x) {
  u32 u = __float_as_uint(x);
  u32 r = u + 0x7FFFu + ((u >> 16) & 1u);
  return (u16)(r >> 16);
}
__device__ inline float bf2f(u16 h) { return __uint_as_float(((u32)h) << 16); }

// async global->LDS, 16B per lane; LDS dest is wave-uniform base + lane*16
__device__ __forceinline__ void gld16(const void* g, void* l) {
  __builtin_amdgcn_global_load_lds(
      (const __attribute__((address_space(1))) unsigned int*)(uintptr_t)g,
      (__attribute__((address_space(3))) unsigned int*)(uintptr_t)l, 16, 0, 0);
}

// ---------------------------------------------------------------------------
// Transpose+split W matrices: W[k][n] fp32 -> Wt_hi/lo[n][k] bf16.
// ---------------------------------------------------------------------------
__global__ __launch_bounds__(256) void convert_w(
    const float* __restrict__ Wq, const float* __restrict__ Wk, const float* __restrict__ Wv,
    u16* __restrict__ qh, u16* __restrict__ qlo2, u16* __restrict__ kh, u16* __restrict__ klo2,
    u16* __restrict__ vh, u16* __restrict__ vlo2) {
  int idx = blockIdx.x * 256 + threadIdx.x;
  const float* src;
  u16 *dh, *dl;
  int KD;
  const int nq = 416 * 256;
  if (idx < nq) {
    src = Wq; dh = qh; dl = qlo2; KD = 416;
  } else if (idx < 2 * nq) {
    idx -= nq; src = Wk; dh = kh; dl = klo2; KD = 416;
  } else {
    idx -= 2 * nq;
    if (idx >= 384 * 256) return;
    src = Wv; dh = vh; dl = vlo2; KD = 384;
  }
  int k = idx >> 8, n = idx & 255;
  float x = src[idx];
  u16 h = f2bf(x);
  dh[n * KD + k] = h;
  dl[n * KD + k] = f2bf(x - bf2f(h));
}

// ---------------------------------------------------------------------------
// Projection GEMM, split-bf16 MFMA: C[m][256] = A[m][KD] @ W[KD][256].
// OUT=0: flat hi/lo [m][256] (Q).
// OUT=1: K (hi only) into kvswz per-(km,kt64) 32768-u16 block (64KB):
//        slot = row*256 + (((c + 5*row)&31)<<3) + e   (row=j&63, c=d>>3, e=d&7)
// OUT=2: V (hi only) at +16384 u16: per-wave(d>>5) region 2048 u16:
//        slot = 16384 + (d>>5)*2048 + ((((j&63)>>3)*32 + (d&31))<<3) + (j&7)
// ---------------------------------------------------------------------------
template <int KD, int OUT>
__global__ __launch_bounds__(256, 3) void proj_mfma(
    const float* __restrict__ A, const u16* __restrict__ wth, const u16* __restrict__ wtl,
    u16* __restrict__ oh, u16* __restrict__ ol) {
  __shared__ u16 Ah[64 * 32], Al[64 * 32];
  __shared__ u16 Wh[256 * 32], Wl[256 * 32];
  const int t = threadIdx.x;
  const int w = t >> 6, l = t & 63;
  const int lr = l & 15, lk = l >> 4;
  const int m0 = blockIdx.x * 64;
  f32x4 acc[16];
#pragma unroll
  for (int i = 0; i < 16; ++i) acc[i] = {};
  const int arow = t >> 2, ac = t & 3;
  const int acp = (ac + (arow >> 1)) & 3;
  for (int k0 = 0; k0 < KD; k0 += 32) {
    __syncthreads();
    {
      const float* s1 = A + (size_t)(m0 + arow) * KD + k0 + ac * 8;
      float4 f1 = *(const float4*)s1;
      float4 f2 = *(const float4*)(s1 + 4);
      float fs[8] = {f1.x, f1.y, f1.z, f1.w, f2.x, f2.y, f2.z, f2.w};
      bf16x8 hv, lv;
#pragma unroll
      for (int j = 0; j < 8; ++j) {
        u16 h = f2bf(fs[j]);
        hv[j] = (short)h;
        lv[j] = (short)f2bf(fs[j] - bf2f(h));
      }
      *(bf16x8*)(Ah + arow * 32 + acp * 8) = hv;
      *(bf16x8*)(Al + arow * 32 + acp * 8) = lv;
#pragma unroll
      for (int i = 0; i < 4; ++i) {
        int ch = t + i * 256;
        int n = ch >> 2, c = ch & 3;
        int cp = (c + (n >> 1)) & 3;
        *(bf16x8*)(Wh + n * 32 + cp * 8) = *(const bf16x8*)(wth + (size_t)n * KD + k0 + c * 8);
        *(bf16x8*)(Wl + n * 32 + cp * 8) = *(const bf16x8*)(wtl + (size_t)n * KD + k0 + c * 8);
      }
    }
    __syncthreads();
    const int row = w * 16 + lr;
    const int rcp = (lk + (row >> 1)) & 3;
    bf16x8 ah = *(const bf16x8*)(Ah + row * 32 + rcp * 8);
    bf16x8 al = *(const bf16x8*)(Al + row * 32 + rcp * 8);
#pragma unroll
    for (int fc = 0; fc < 16; ++fc) {
      int n = lr + 16 * fc;
      int cp = (lk + (n >> 1)) & 3;
      bf16x8 bh = *(const bf16x8*)(Wh + n * 32 + cp * 8);
      bf16x8 bl = *(const bf16x8*)(Wl + n * 32 + cp * 8);
      acc[fc] = MFMA32(ah, bh, acc[fc]);
      acc[fc] = MFMA32(ah, bl, acc[fc]);
      acc[fc] = MFMA32(al, bh, acc[fc]);
    }
  }
  if (OUT == 0) {
#pragma unroll
    for (int fc = 0; fc < 16; ++fc) {
      int n = lr + 16 * fc;
#pragma unroll
      for (int r = 0; r < 4; ++r) {
        int m = m0 + w * 16 + lk * 4 + r;
        float v = acc[fc][r];
        u16 h = f2bf(v);
        oh[(size_t)m * 256 + n] = h;
        ol[(size_t)m * 256 + n] = f2bf(v - bf2f(h));
      }
    }
  } else if (OUT == 1) {
#pragma unroll
    for (int r = 0; r < 4; ++r) {
      int m = m0 + w * 16 + lk * 4 + r;
      int km = m / 576;
      int j = m - km * 576;
      int kt = j >> 6, row = j & 63;
      size_t rowbase = (size_t)(km * 9 + kt) * 32768 + (row << 8);
#pragma unroll
      for (int fc = 0; fc < 16; ++fc) {
        int c = (lr >> 3) + 2 * fc;
        size_t slot = rowbase + (size_t)((((c + 5 * row) & 31) << 3) + (lr & 7));
        oh[slot] = f2bf(acc[fc][r]);
      }
    }
  } else {
    const int km = m0 / 576;
    const int j0 = (m0 % 576) + w * 16 + lk * 4;
    const int kt = j0 >> 6;
    const int jl = j0 & 63;
    const int kc = jl >> 3, e0 = jl & 7;
    const size_t vbase = (size_t)(km * 9 + kt) * 32768 + 16384;
#pragma unroll
    for (int fc = 0; fc < 16; ++fc) {
      // d = lr + 16*fc -> region fc>>1, d&31 = lr + (fc&1)*16
      size_t slot = vbase + (size_t)((fc >> 1) * 2048 + ((kc * 32 + lr + (fc & 1) * 16) << 3) + e0);
      u16 hs[4];
#pragma unroll
      for (int r = 0; r < 4; ++r) hs[r] = f2bf(acc[fc][r]);
      *(ushort4*)(oh + slot) = make_ushort4(hs[0], hs[1], hs[2], hs[3]);
    }
  }
}

// ---------------------------------------------------------------------------
// Flash attention: 512 thr / 8 waves = (wq 0..3) x (wk 0..1); 64 q x 64 keys/kt
// (9 iterations).  S = qh*kh bf16 MFMA (Q-lo dropped this round); PV = ph*vh.
// Per wave-kt: 16 K reads + 16 MFMA (QK), 2 P b64 writes, 8 P reads + 4 V
// reads + 16 MFMA (PV), 8 staging DMAs.  2 barriers/kt, counted vmcnt only.
// m==0 softmax, stats reduced once at end.  R written [b,km][d][n] normalized.
// ---------------------------------------------------------------------------
__global__ __launch_bounds__(512, 4) void attn_kernel(
    const u16* __restrict__ qhi, const u16* __restrict__ kvswz,
    float* __restrict__ rpartT, float* __restrict__ invl) {
  __shared__ u16 KV[32768];  // u16: [Kh 16384 = 64 rows x 256][Vh 16384]
  __shared__ u16 Ph[64 * 72];
  __shared__ float lred[2][64], mred[2][64];
  __shared__ float invs[64];
  const int t = threadIdx.x;
  const int w = t >> 6, l = t & 63;
  const int lr = l & 15, lk = l >> 4;
  const int wq = w >> 1, wk = w & 1;
  // XCD-cluster swizzle: all 36 blocks of one km land on xcd = km%8.
  const int L = blockIdx.x;
  const int xcd = L & 7, slot = L >> 3;
  const int km = xcd + 8 * (slot / 36);
  const int inner = slot % 36;
  const int b = inner & 3, qb = inner >> 2;
  const int qw = qb * 64 + wq * 16;

  // Q fragments (B-operand of swapped QK: col=q=lr, k-chunk lk*8 + s*32)
  bf16x8 qh[8];
  {
    const size_t qoff = ((size_t)(b * 576 + qw + lr)) * 256 + lk * 8;
#pragma unroll
    for (int s = 0; s < 8; ++s) qh[s] = *(const bf16x8*)(qhi + qoff + s * 32);
  }

  f32x4 o[4][2];
#pragma unroll
  for (int i = 0; i < 4; ++i)
#pragma unroll
    for (int j = 0; j < 2; ++j) o[i][j] = {};
  float m_part = -1e30f, l_part = 0.f;  // per-lane: q=wq*16+lr, keys of wk half

  const char* kvb = (const char*)kvswz + (size_t)(km * 9) * 65536;
  char* lds0 = (char*)&KV[0];

  auto STAGE_K = [&](int kt) {
    const char* src = kvb + (size_t)kt * 65536 + t * 16;
    char* dst = lds0 + t * 16;
#pragma unroll
    for (int i = 0; i < 4; ++i) gld16(src + i * 8192, dst + i * 8192);
  };
  auto STAGE_V = [&](int kt) {
    // wave-self slice: bytes 32768 + w*4096 .. +4096
    const char* src = kvb + (size_t)kt * 65536 + 32768 + w * 4096 + l * 16;
    char* dst = lds0 + 32768 + w * 4096 + l * 16;
#pragma unroll
    for (int c = 0; c < 4; ++c) gld16(src + c * 1024, dst + c * 1024);
  };

  // prologue
  asm volatile("s_waitcnt vmcnt(0)" ::: "memory");  // Q drained: clean FIFO
  __builtin_amdgcn_sched_barrier(0);
  STAGE_K(0);
  __builtin_amdgcn_sched_barrier(0);
  STAGE_V(0);
  asm volatile("s_waitcnt vmcnt(4)" ::: "memory");  // K(0) landed, V(0) in flight
  __builtin_amdgcn_sched_barrier(0);
  __builtin_amdgcn_s_barrier();
  __builtin_amdgcn_sched_barrier(0);

  const int krow0 = wk * 32 + lr;
  const int krow1 = wk * 32 + 16 + lr;

  for (int kt = 0; kt < 9; ++kt) {
    // ---- QK^T: A = K-frags (two 16-key blocks of wk half), B = Q
    f32x4 s0 = {}, s1 = {};
    __builtin_amdgcn_s_setprio(1);
#pragma unroll
    for (int s = 0; s < 8; ++s) {
      const int cc0 = ((s * 4 + lk) + 5 * krow0) & 31;
      const int cc1 = ((s * 4 + lk) + 5 * krow1) & 31;
      bf16x8 k0 = *(const bf16x8*)(KV + krow0 * 256 + cc0 * 8);
      bf16x8 k1 = *(const bf16x8*)(KV + krow1 * 256 + cc1 * 8);
      s0 = MFMA32(k0, qh[s], s0);
      s1 = MFMA32(k1, qh[s], s1);
    }
    __builtin_amdgcn_s_setprio(0);

    // ---- P = exp(S*scale): lane q = wq*16+lr; keys wk*32 + {lk*4.., 16+lk*4..}
    ushort4 p0, p1;
#pragma unroll
    for (int r = 0; r < 4; ++r) {
      float a0 = s0[r] * SCALE;
      float a1 = s1[r] * SCALE;
      m_part = fmaxf(m_part, fmaxf(a0, a1));
      float e0 = __expf(a0), e1 = __expf(a1);
      l_part += e0 + e1;
      (&p0.x)[r] = f2bf(e0);
      (&p1.x)[r] = f2bf(e1);
    }
    {
      int pb = (wq * 16 + lr) * 72 + wk * 32 + lk * 4;
      *(ushort4*)(Ph + pb) = p0;
      *(ushort4*)(Ph + pb + 16) = p1;
    }
    asm volatile("s_waitcnt lgkmcnt(0)" ::: "memory");  // K reads + P writes done
    __builtin_amdgcn_sched_barrier(0);
    __builtin_amdgcn_s_barrier();  // B1: P visible, K region free
    __builtin_amdgcn_sched_barrier(0);

    const int ktn = kt < 8 ? kt + 1 : 8;
    STAGE_K(ktn);  // flies under PV
    __builtin_amdgcn_sched_barrier(0);
    asm volatile("s_waitcnt vmcnt(4)" ::: "memory");  // my V(kt) landed
    __builtin_amdgcn_sched_barrier(0);

    // ---- PV: wave covers d = w*32 + dt*16 + lr, keys in two 32-halves (ks)
    __builtin_amdgcn_s_setprio(1);
#pragma unroll
    for (int ks = 0; ks < 2; ++ks) {
      bf16x8 vhf[2];
#pragma unroll
      for (int dt = 0; dt < 2; ++dt)
        vhf[dt] = *(const bf16x8*)(KV + 16384 + w * 2048 + ((ks * 4 + lk) * 32 + dt * 16 + lr) * 8);
#pragma unroll
      for (int qt = 0; qt < 4; ++qt) {
        bf16x8 pah = *(const bf16x8*)(Ph + (qt * 16 + lr) * 72 + ks * 32 + lk * 8);
#pragma unroll
        for (int dt = 0; dt < 2; ++dt)
          o[qt][dt] = MFMA32(pah, vhf[dt], o[qt][dt]);
      }
    }
    __builtin_amdgcn_s_setprio(0);
    asm volatile("s_waitcnt lgkmcnt(0)" ::: "memory");  // V/P reads done
    __builtin_amdgcn_sched_barrier(0);
    STAGE_V(ktn);  // safe: only this wave reads its V slice
    __builtin_amdgcn_sched_barrier(0);
    asm volatile("s_waitcnt vmcnt(4)" ::: "memory");  // my K(kt+1) landed
    __builtin_amdgcn_sched_barrier(0);
    __builtin_amdgcn_s_barrier();  // B2: all K landed, P region free
    __builtin_amdgcn_sched_barrier(0);
  }

  // ---- stats: lane q=wq*16+lr; combine lk groups then wk halves
  {
    float lv = l_part, mv = m_part;
    lv += __shfl_xor(lv, 16, 64);
    mv = fmaxf(mv, __shfl_xor(mv, 16, 64));
    lv += __shfl_xor(lv, 32, 64);
    mv = fmaxf(mv, __shfl_xor(mv, 32, 64));
    if (l < 16) {
      lred[wk][wq * 16 + l] = lv;
      mred[wk][wq * 16 + l] = mv;
    }
  }
  __syncthreads();
  if (w == 0) {
    float ls = lred[0][l] + lred[1][l];
    float mv = fmaxf(mred[0][l], mred[1][l]);
    invs[l] = 1.0f / ls;
    invl[(size_t)(b * 80 + km) * 576 + qb * 64 + l] = __expf(mv) / ls;
  }
  __syncthreads();

  float* dst = rpartT + (size_t)(b * 80 + km) * 147456;
#pragma unroll
  for (int qt = 0; qt < 4; ++qt) {
    float iv[4];
#pragma unroll
    for (int r = 0; r < 4; ++r) iv[r] = invs[qt * 16 + lk * 4 + r];
#pragma unroll
    for (int dt = 0; dt < 2; ++dt) {
      int d = w * 32 + dt * 16 + lr;
      f32x4 vv;
      vv[0] = o[qt][dt][0] * iv[0];
      vv[1] = o[qt][dt][1] * iv[1];
      vv[2] = o[qt][dt][2] * iv[2];
      vv[3] = o[qt][dt][3] * iv[3];
      *(f32x4*)(dst + (size_t)d * 576 + qb * 64 + qt * 16 + lk * 4) = vv;
    }
  }
}

// ---------------------------------------------------------------------------
// Weights: s[b,k,m] = mean_n 1/l_ref ; w = gate(p) * s / (sum_m s + 1e-8)
// ---------------------------------------------------------------------------
__global__ __launch_bounds__(256) void weight_kernel(const float* __restrict__ invl,
                                                     const float* __restrict__ p,
                                                     float* __restrict__ wout) {
  const int k = blockIdx.x, b = blockIdx.y;
  __shared__ float sm[10];
  __shared__ float red[4];
  const int t = threadIdx.x;
  for (int m = 0; m < 10; ++m) {
    float part = 0.f;
    for (int n = t; n < 576; n += 256)
      part += invl[(size_t)((b * 8 + k) * 10 + m) * 576 + n];
#pragma unroll
    for (int off = 32; off; off >>= 1) part += __shfl_down(part, off, 64);
    if ((t & 63) == 0) red[t >> 6] = part;
    __syncthreads();
    if (t == 0) sm[m] = (red[0] + red[1] + red[2] + red[3]) * (1.0f / 576.0f);
    __syncthreads();
  }
  if (t == 0) {
    float tot = 0.f;
    for (int m = 0; m < 10; ++m) tot += sm[m];
    float pmax = fmaxf(fmaxf(p[0 * 8 + k], p[1 * 8 + k]), fmaxf(p[2 * 8 + k], p[3 * 8 + k]));
    float gate = (pmax >= 0.01f) ? p[b * 8 + k] : 0.0f;
    for (int m = 0; m < 10; ++m)
      wout[(b * 8 + k) * 10 + m] = gate * sm[m] / (tot + 1e-8f);
  }
}

// ---------------------------------------------------------------------------
// out[b][d][n] = sum_km w[b,km] * rpartT[b,km][d][n]
// ---------------------------------------------------------------------------
__global__ __launch_bounds__(256) void reduce_out_k(const float* __restrict__ rpartT,
                                                    const float* __restrict__ wbuf,
                                                    float* __restrict__ out) {
  int idx = blockIdx.x * 256 + threadIdx.x;
  int b = idx / 147456;
  size_t off = (size_t)(idx % 147456);
  const float* base = rpartT + (size_t)b * 80 * 147456 + off;
  const float* wp = wbuf + b * 80;
  float acc = 0.f;
#pragma unroll 8
  for (int g = 0; g < 80; ++g) acc += wp[g] * base[(size_t)g * 147456];
  out[idx] = acc;
}

// ---------------------------------------------------------------------------
extern "C" void kernel_launch(void* const* d_in, const int* in_sizes, int n_in,
                              void* d_out, int out_size, void* d_ws, size_t ws_size,
                              hipStream_t stream) {
  const float* Q = (const float*)d_in[0];
  const float* dbk = (const float*)d_in[1];
  const float* dbv = (const float*)d_in[2];
  const float* p = (const float*)d_in[3];
  const float* Wq = (const float*)d_in[4];
  const float* Wk = (const float*)d_in[5];
  const float* Wv = (const float*)d_in[6];
  float* out = (float*)d_out;
  char* ws = (char*)d_ws;

  u16* qhi = (u16*)(ws);                    // 1,179,648 B
  u16* qlo = (u16*)(ws + 1179648);          // 1,179,648 B
  u16* kvswz = (u16*)(ws + 2359296);        // 80*9*65536 = 47,185,920 B
  float* invl = (float*)(ws + 49545216);    // 737,280 B
  float* wbuf = (float*)(ws + 50282496);    // 1,280 B
  float* rpartT = (float*)(ws + 50283776);  // 188,743,680 B
  // W^T hi/lo temporaries aliased into rpartT region (consumed before attn writes)
  u16* wqh = (u16*)(ws + 50283776);
  u16* wql = wqh + 106496;
  u16* wkh = wql + 106496;
  u16* wkl = wkh + 106496;
  u16* wvh = wkl + 106496;
  u16* wvl = wvh + 98304;

  convert_w<<<1216, 256, 0, stream>>>(Wq, Wk, Wv, wqh, wql, wkh, wkl, wvh, wvl);
  proj_mfma<416, 0><<<36, 256, 0, stream>>>(Q, wqh, wql, qhi, qlo);
  proj_mfma<416, 1><<<720, 256, 0, stream>>>(dbk, wkh, wkl, kvswz, nullptr);
  proj_mfma<384, 2><<<720, 256, 0, stream>>>(dbv, wvh, wvl, kvswz, nullptr);
  attn_kernel<<<2880, 512, 0, stream>>>(qhi, kvswz, rpartT, invl);
  weight_kernel<<<dim3(8, 4), 256, 0, stream>>>(invl, p, wbuf);
  reduce_out_k<<<2304, 256, 0, stream>>>(rpartT, wbuf, out);
}